// Round 7
// baseline (142.556 us; speedup 1.0000x reference)
//
#include <hip/hip_runtime.h>
#include <cstdint>
#include <cstddef>

#define KCAT 384
#define NPB  16       // nodes per fused block (8 waves x 2 nodes)
#define AST  264      // LDS A row stride elems (528B) — only [x | mean] stored
#define VP_BLOCKS 24  // prep blocks packing Vp

typedef __attribute__((ext_vector_type(8))) short bf16x8;
typedef __attribute__((ext_vector_type(4))) float f32x4;

static __device__ __forceinline__ unsigned short f2bf(float f) {
    unsigned int u = __builtin_bit_cast(unsigned int, f);
    u += 0x7fffu + ((u >> 16) & 1u);
    return (unsigned short)(u >> 16);
}
static __device__ __forceinline__ float bfhi(unsigned int u) { return __builtin_bit_cast(float, u & 0xFFFF0000u); }
static __device__ __forceinline__ float bflo(unsigned int u) { return __builtin_bit_cast(float, u << 16); }
// masked bf16x8 accumulate: m = all-ones keeps, 0 zeroes (bf16 0x0000 == +0.0)
static __device__ __forceinline__ void acc8(float* a, const uint4& v, unsigned m) {
    unsigned x0 = v.x & m, x1 = v.y & m, x2 = v.z & m, x3 = v.w & m;
    a[0] += bflo(x0); a[1] += bfhi(x0); a[2] += bflo(x1); a[3] += bfhi(x1);
    a[4] += bflo(x2); a[5] += bfhi(x2); a[6] += bflo(x3); a[7] += bfhi(x3);
}

// ---------------- Prep: Vp pack (GEMM B layout), xb = bf16(x), blkoff ----------------
// Vp: element ((g*12 + s)*64 + lane)*8 + j = W[g*16 + (lane&15)][s*32 + (lane>>4)*8 + j]
// -> a wave's B-fragment for (col-group g, kstep s) is ONE contiguous 1KB read.
__global__ __launch_bounds__(256)
void prep(const float* __restrict__ x, const float* __restrict__ Wg,
          const float* __restrict__ Wl, const float* __restrict__ Ws,
          const int* __restrict__ dst, unsigned short* __restrict__ Vp,
          unsigned short* __restrict__ xb, int* __restrict__ blkoff,
          int total8, int nblk, int noffb, int E) {
    const int bx = blockIdx.x, t = threadIdx.x;
    if (bx < VP_BLOCKS) {
        int gid = bx * 256 + t;
        if (gid < 6144) {
            int l = gid & 63, srow = (gid >> 6) % 12, g = gid / 768;
            int o = g * 16 + (l & 15);
            int k = srow * 32 + (l >> 4) * 8;
            const float* w; int kk;
            if (k < 128)      { w = Wg; kk = k; }
            else if (k < 256) { w = Wl; kk = k - 128; }
            else              { w = Ws; kk = k - 256; }
            const float* p = w + o * 128 + kk;
            uint4 u;
            u.x = (unsigned)f2bf(p[0]) | ((unsigned)f2bf(p[1]) << 16);
            u.y = (unsigned)f2bf(p[2]) | ((unsigned)f2bf(p[3]) << 16);
            u.z = (unsigned)f2bf(p[4]) | ((unsigned)f2bf(p[5]) << 16);
            u.w = (unsigned)f2bf(p[6]) | ((unsigned)f2bf(p[7]) << 16);
            ((uint4*)Vp)[gid] = u;
        }
    } else if (bx < VP_BLOCKS + noffb) {
        int b = (bx - VP_BLOCKS) * 256 + t;
        if (b < nblk) {
            int target = b * NPB;
            int lo = 0, hi = E;
            while (lo < hi) { int mid = (lo + hi) >> 1; if (dst[mid] < target) lo = mid + 1; else hi = mid; }
            blkoff[b] = lo;
        }
    } else {
        int gid = (bx - VP_BLOCKS - noffb) * 256 + t;
        if (gid < total8) {
            const float4* px = (const float4*)x + (size_t)gid * 2;
            float4 a = px[0], bq = px[1];
            uint4 u;
            u.x = (unsigned)f2bf(a.x)  | ((unsigned)f2bf(a.y)  << 16);
            u.y = (unsigned)f2bf(a.z)  | ((unsigned)f2bf(a.w)  << 16);
            u.z = (unsigned)f2bf(bq.x) | ((unsigned)f2bf(bq.y) << 16);
            u.w = (unsigned)f2bf(bq.z) | ((unsigned)f2bf(bq.w) << 16);
            ((uint4*)xb)[gid] = u;
        }
    }
}

// ---------------- Fused: gather (2 nodes/wave, all loads up-front) -> LDS -> MFMA -> ELU ----------------
// 512 threads = 8 waves, 16 nodes/block, 3125 blocks. VGPR cap 128 (16 uint4 row-bufs
// in flight). Phase 2: wave wv owns col-group wv (16 cols); A broadcast from LDS;
// mask.x K-segment synthesized by ANDing the x fragment; B prefetched from packed Vp.
__global__ __launch_bounds__(512, 4)
void fused(const unsigned short* __restrict__ xb, const int* __restrict__ src,
           const int* __restrict__ deg, const int* __restrict__ blkoff,
           const unsigned short* __restrict__ Vp, const float* __restrict__ bias,
           float* __restrict__ out, int N) {
    __shared__ __align__(16) unsigned short As[NPB * AST];   // 8448 B
    __shared__ unsigned smask[NPB];
    const int t = threadIdx.x, wv = t >> 6, lane = t & 63;
    const int c = lane & 15, p = lane >> 4;
    const int base = blockIdx.x * NPB;

    // per-block deg scan (redundant per wave; broadcast loads, no barrier needed yet)
    int dg = 0;
    if (lane < NPB && base + lane < N) dg = deg[base + lane];
    int incl = dg;
#pragma unroll
    for (int off = 1; off < NPB; off <<= 1) {
        int v = __shfl_up(incl, off, 64);
        if (lane >= off) incl += v;
    }
    const int blk = blkoff[blockIdx.x];
    const int nA = 2 * wv, nB = 2 * wv + 1;
    const int dA = __shfl(dg, nA, 64),  dB = __shfl(dg, nB, 64);
    const int sA = blk + __shfl(incl, nA, 64) - dA;
    const int sB = blk + __shfl(incl, nB, 64) - dB;
    if (wv == 0 && lane < NPB) smask[lane] = (dg > 0) ? 0xFFFFFFFFu : 0u;

    int idxA = 0, idxB = 0;
    if (lane < dA) idxA = src[sA + lane];
    if (lane < dB) idxB = src[sB + lane];

    const uint4* x4 = (const uint4*)xb;
    // self rows (p==1 loads node A's, p==2 loads node B's)
    uint4 xvA = {0,0,0,0}, xvB = {0,0,0,0};
    if (p == 1 && base + nA < N) xvA = x4[(size_t)(base + nA) * 16 + c];
    if (p == 2 && base + nB < N) xvB = x4[(size_t)(base + nB) * 16 + c];

    // batch-1 row loads for BOTH nodes, issued before any accumulate (8 uint4)
    int a0i = __shfl(idxA, p, 64),      a1i = __shfl(idxA, p + 4, 64);
    int a2i = __shfl(idxA, p + 8, 64),  a3i = __shfl(idxA, p + 12, 64);
    int b0i = __shfl(idxB, p, 64),      b1i = __shfl(idxB, p + 4, 64);
    int b2i = __shfl(idxB, p + 8, 64),  b3i = __shfl(idxB, p + 12, 64);
    uint4 vA0 = x4[(size_t)a0i * 16 + c], vA1 = x4[(size_t)a1i * 16 + c];
    uint4 vA2 = x4[(size_t)a2i * 16 + c], vA3 = x4[(size_t)a3i * 16 + c];
    uint4 vB0 = x4[(size_t)b0i * 16 + c], vB1 = x4[(size_t)b1i * 16 + c];
    uint4 vB2 = x4[(size_t)b2i * 16 + c], vB3 = x4[(size_t)b3i * 16 + c];
    // batch-2 loads (wave-uniform guards), also before accumulation (up to 8 more)
    uint4 vA4, vA5, vA6, vA7, vB4, vB5, vB6, vB7;
    const bool twoA = (dA > 16), twoB = (dB > 16);
    if (twoA) {
        int e = 16 + p;
        int r4 = __shfl(idxA, e, 64),      r5 = __shfl(idxA, e + 4, 64);
        int r6 = __shfl(idxA, e + 8, 64),  r7 = __shfl(idxA, e + 12, 64);
        vA4 = x4[(size_t)r4 * 16 + c]; vA5 = x4[(size_t)r5 * 16 + c];
        vA6 = x4[(size_t)r6 * 16 + c]; vA7 = x4[(size_t)r7 * 16 + c];
    }
    if (twoB) {
        int e = 16 + p;
        int r4 = __shfl(idxB, e, 64),      r5 = __shfl(idxB, e + 4, 64);
        int r6 = __shfl(idxB, e + 8, 64),  r7 = __shfl(idxB, e + 12, 64);
        vB4 = x4[(size_t)r4 * 16 + c]; vB5 = x4[(size_t)r5 * 16 + c];
        vB6 = x4[(size_t)r6 * 16 + c]; vB7 = x4[(size_t)r7 * 16 + c];
    }

    float aA[8] = {0,0,0,0,0,0,0,0}, bA[8] = {0,0,0,0,0,0,0,0};
    float aB[8] = {0,0,0,0,0,0,0,0}, bB[8] = {0,0,0,0,0,0,0,0};
    acc8(aA, vA0, (p      < dA) ? ~0u : 0u);
    acc8(bA, vA1, (p + 4  < dA) ? ~0u : 0u);
    acc8(aA, vA2, (p + 8  < dA) ? ~0u : 0u);
    acc8(bA, vA3, (p + 12 < dA) ? ~0u : 0u);
    acc8(aB, vB0, (p      < dB) ? ~0u : 0u);
    acc8(bB, vB1, (p + 4  < dB) ? ~0u : 0u);
    acc8(aB, vB2, (p + 8  < dB) ? ~0u : 0u);
    acc8(bB, vB3, (p + 12 < dB) ? ~0u : 0u);
    if (twoA) {
        int e = 16 + p;
        acc8(aA, vA4, (e      < dA) ? ~0u : 0u);
        acc8(bA, vA5, (e + 4  < dA) ? ~0u : 0u);
        acc8(aA, vA6, (e + 8  < dA) ? ~0u : 0u);
        acc8(bA, vA7, (e + 12 < dA) ? ~0u : 0u);
    }
    if (twoB) {
        int e = 16 + p;
        acc8(aB, vB4, (e      < dB) ? ~0u : 0u);
        acc8(bB, vB5, (e + 4  < dB) ? ~0u : 0u);
        acc8(aB, vB6, (e + 8  < dB) ? ~0u : 0u);
        acc8(bB, vB7, (e + 12 < dB) ? ~0u : 0u);
    }
#pragma unroll
    for (int i = 0; i < 8; ++i) { aA[i] += bA[i]; aB[i] += bB[i]; }
#pragma unroll
    for (int i = 0; i < 8; ++i) {
        aA[i] += __shfl_xor(aA[i], 16, 64);
        aA[i] += __shfl_xor(aA[i], 32, 64);
        aB[i] += __shfl_xor(aB[i], 16, 64);
        aB[i] += __shfl_xor(aB[i], 32, 64);
    }
    // LDS panel: row = [x(128) | mean(128)] bf16, stride 264
    if (p == 1) *(uint4*)(As + nA * AST + c * 8) = xvA;
    if (p == 2) *(uint4*)(As + nB * AST + c * 8) = xvB;
    if (p == 0) {
        float inv = (dA > 0) ? 1.0f / (float)dA : 0.0f;
        uint4 u;
        u.x = (unsigned)f2bf(aA[0]*inv) | ((unsigned)f2bf(aA[1]*inv) << 16);
        u.y = (unsigned)f2bf(aA[2]*inv) | ((unsigned)f2bf(aA[3]*inv) << 16);
        u.z = (unsigned)f2bf(aA[4]*inv) | ((unsigned)f2bf(aA[5]*inv) << 16);
        u.w = (unsigned)f2bf(aA[6]*inv) | ((unsigned)f2bf(aA[7]*inv) << 16);
        *(uint4*)(As + nA * AST + 128 + c * 8) = u;
    }
    if (p == 3) {
        float inv = (dB > 0) ? 1.0f / (float)dB : 0.0f;
        uint4 u;
        u.x = (unsigned)f2bf(aB[0]*inv) | ((unsigned)f2bf(aB[1]*inv) << 16);
        u.y = (unsigned)f2bf(aB[2]*inv) | ((unsigned)f2bf(aB[3]*inv) << 16);
        u.z = (unsigned)f2bf(aB[4]*inv) | ((unsigned)f2bf(aB[5]*inv) << 16);
        u.w = (unsigned)f2bf(aB[6]*inv) | ((unsigned)f2bf(aB[7]*inv) << 16);
        *(uint4*)(As + nB * AST + 128 + c * 8) = u;
    }
    __syncthreads();

    // ---- Phase 2: wave wv -> col-group wv. 12 k-steps, B prefetched from Vp.
    const int quad = p;
    const unsigned msk = smask[c];
    const bf16x8* VB = (const bf16x8*)Vp;
    f32x4 acc = (f32x4){0.f, 0.f, 0.f, 0.f};
    bf16x8 bfr = VB[(wv * 12) * 64 + lane];
#pragma unroll
    for (int s = 0; s < 12; ++s) {
        int sn = (s + 1 < 12) ? s + 1 : 0;
        bf16x8 nxt = VB[(wv * 12 + sn) * 64 + lane];
        int seg = s >> 2, kk = (s & 3) * 32;
        bf16x8 afr = *(const bf16x8*)(As + c * AST + (seg == 1 ? 128 : 0) + kk + quad * 8);
        if (seg == 2) {
            uint4 ai = __builtin_bit_cast(uint4, afr);
            ai.x &= msk; ai.y &= msk; ai.z &= msk; ai.w &= msk;
            afr = __builtin_bit_cast(bf16x8, ai);
        }
        acc = __builtin_amdgcn_mfma_f32_16x16x32_bf16(afr, bfr, acc, 0, 0, 0);
        bfr = nxt;
    }

    // epilogue: + bias, ELU, store. C/D: col=lane&15, row=quad*4+reg
    const int col = wv * 16 + c;
    const float bv = bias[col];
#pragma unroll
    for (int reg = 0; reg < 4; ++reg) {
        int grow = base + quad * 4 + reg;
        if (grow < N) {
            float v = acc[reg] + bv;
            out[(size_t)grow * 128 + col] = (v > 0.f) ? v : __expf(v) - 1.0f;
        }
    }
}

extern "C" void kernel_launch(void* const* d_in, const int* in_sizes, int n_in,
                              void* d_out, int out_size, void* d_ws, size_t ws_size,
                              hipStream_t stream) {
    const float* x  = (const float*)d_in[0];
    const float* Wg = (const float*)d_in[1];
    const float* Wl = (const float*)d_in[2];
    const float* Ws = (const float*)d_in[3];
    const float* b  = (const float*)d_in[4];
    const int*   src = (const int*)d_in[5];
    const int*   dst = (const int*)d_in[6];
    const int*   deg = (const int*)d_in[7];
    const int E = in_sizes[5];
    const int N = in_sizes[7];
    float* out = (float*)d_out;

    unsigned short* Vp     = (unsigned short*)d_ws;              // 96 KB (packed B)
    int*            blkoff = (int*)((char*)d_ws + 98304);        // 32 KB reserved
    unsigned short* xb     = (unsigned short*)((char*)d_ws + 131072);  // 12.8 MB

    const int nblk   = (N + NPB - 1) / NPB;        // 3125
    const int noffb  = (nblk + 255) / 256;         // 13
    const int total8 = N * 16;
    const int nconv  = (total8 + 255) / 256;       // 3125

    prep<<<dim3(VP_BLOCKS + noffb + nconv), dim3(256), 0, stream>>>(
        x, Wg, Wl, Ws, dst, Vp, xb, blkoff, total8, nblk, noffb, E);
    fused<<<dim3(nblk), dim3(512), 0, stream>>>(xb, src, deg, blkoff, Vp, b, out, N);
}